// Round 4
// baseline (100.468 us; speedup 1.0000x reference)
//
#include <hip/hip_runtime.h>
#include <hip/hip_bf16.h>
#include <math.h>

// FluxHead: B=4, T=4096, D_MODEL=1024, HEAD_DIM=128, STRIDE=4, Tk=1024, CAUSAL
// Exact-math simplifications:
//  - spectral gate adds a per-(b,q) scalar to logits -> softmax-invariant -> skipped
//  - reverse branch == unmasked forward attention, output read at mirror row
//  - pooling commutes with K/V projection -> pooled in GEMM epilogue (lane-local)
//  - log2e/SCALE folded into Wq -> softmax in exp2 units

#define T_ 4096
#define TK_ 1024

typedef __attribute__((ext_vector_type(8))) short bf16x8;
typedef __attribute__((ext_vector_type(4))) float f32x4;
typedef __attribute__((ext_vector_type(4))) short s16x4;
typedef __attribute__((address_space(1))) unsigned int gas_u32;
typedef __attribute__((address_space(3))) unsigned int las_u32;

__device__ inline short f2bf(float f) {
  unsigned u = __builtin_bit_cast(unsigned, f);
  u = (u + 0x7FFFu + ((u >> 16) & 1u)) >> 16;
  return (short)u;
}
__device__ inline f32x4 mfma16(bf16x8 a, bf16x8 b, f32x4 c) {
  return __builtin_amdgcn_mfma_f32_16x16x32_bf16(a, b, c, 0, 0, 0);
}
__device__ inline void gll16(const void* g, void* l) {
  __builtin_amdgcn_global_load_lds((gas_u32*)g, (las_u32*)l, 16, 0, 0);
}
#define VMCNT(n) asm volatile("s_waitcnt vmcnt(" #n ")" ::: "memory")

// ---- rope table: cos/sin[t][d], t<4096, d<64 ----
__global__ __launch_bounds__(256) void rope_kernel(float* __restrict__ cosT,
                                                   float* __restrict__ sinT) {
  int i = blockIdx.x * 256 + threadIdx.x;  // 262144
  int t = i >> 6, d = i & 63;
  float theta = powf(10000.f, -(float)d * (1.f / 64.f));
  float fr = (float)t * theta;
  cosT[i] = cosf(fr);
  sinT[i] = sinf(fr);
}

// ---- WT prep: plain [384][1024] bf16, custom row order so each 96-row
// wave-slice has matched rope lo/hi pairs:
// w0: rows 0..47 Qlo d0..47 | 48..95 Qhi d0..47
// w1: 96..111 Qlo d48..63 | 112..127 Qhi d48..63 | 128..159 Klo d0..31 | 160..191 Khi d0..31
// w2: 192..223 Klo d32..63 | 224..255 Khi d32..63 | 256..287 V d0..31
// w3: 288..383 V d32..127
__global__ __launch_bounds__(256) void wtprep_kernel(const float* __restrict__ Wq,
                                                     const float* __restrict__ Wk,
                                                     const float* __restrict__ Wv,
                                                     short* __restrict__ WT) {
  int i = blockIdx.x * 256 + threadIdx.x;  // 384*1024
  int n = i >> 10, k = i & 1023;
  const float* W;
  int col;
  float s = 1.f;
  if (n < 128) {
    W = Wq;
    s = 0.12751741656f;  // log2(e)/sqrt(128)
    if (n < 48) col = n;
    else if (n < 96) col = n + 16;
    else if (n < 112) col = n - 48;
    else col = n;
  } else if (n < 256) {
    W = Wk;
    if (n < 160) col = n - 128;
    else if (n < 192) col = n - 96;
    else if (n < 224) col = n - 160;
    else col = n - 128;
  } else {
    W = Wv;
    col = n - 256;
  }
  WT[i] = f2bf(W[(size_t)k * 128 + col] * s);
}

// ---- fused projection GEMM: grid 512, block 256 (4 waves).
// Block = 32 M-rows; wave w = 32 M x 96 N (N-slice rows [w*96, w*96+96)).
// x tile staged in LDS (bf16, XOR-swz, dbuf, 16 KB); W fragments direct from L2.
__global__ __launch_bounds__(256) void gemm_fused(const float* __restrict__ x,
                                                  const short* __restrict__ WT,
                                                  const float* __restrict__ cosT,
                                                  const float* __restrict__ sinT,
                                                  short* __restrict__ Qb,
                                                  char* __restrict__ Kswz,
                                                  char* __restrict__ Vswz) {
  __shared__ __align__(16) char Xl[2][8192];  // 32 rows x 64 k bf16, pitch 128B, XOR swz
  const int tid = threadIdx.x;
  const int w = tid >> 6, g = (tid >> 4) & 3, c = tid & 15;
  const int m0 = blockIdx.x * 32;
  const int srow = tid >> 3, skp = tid & 7;
  const int swc = (c & 7) << 4;
  const int sws = (srow & 7) << 4;

  f32x4 acc[2][6];
#pragma unroll
  for (int mf = 0; mf < 2; mf++)
#pragma unroll
    for (int n = 0; n < 6; n++) acc[mf][n] = (f32x4){0.f, 0.f, 0.f, 0.f};

  const float* xs = x + (size_t)(m0 + srow) * 1024;
  const short* wb = WT + (size_t)(w * 96 + c) * 1024;

  auto XW = [&](int buf, float4 f0, float4 f1) {
    s16x4 a = {f2bf(f0.x), f2bf(f0.y), f2bf(f0.z), f2bf(f0.w)};
    s16x4 b = {f2bf(f1.x), f2bf(f1.y), f2bf(f1.z), f2bf(f1.w)};
    *(s16x4*)(Xl[buf] + srow * 128 + ((skp * 8) ^ sws)) = a;
    *(s16x4*)(Xl[buf] + srow * 128 + ((64 + skp * 8) ^ sws)) = b;
  };

  {
    float4 f0 = *(const float4*)(xs + skp * 4);
    float4 f1 = *(const float4*)(xs + skp * 4 + 32);
    XW(0, f0, f1);
  }
  __syncthreads();

#pragma unroll 2
  for (int ki = 0; ki < 16; ki++) {
    const int cur = ki & 1;
    float4 g0, g1;
    if (ki < 15) {
      g0 = *(const float4*)(xs + (ki + 1) * 64 + skp * 4);
      g1 = *(const float4*)(xs + (ki + 1) * 64 + skp * 4 + 32);
    }
    bf16x8 af[2][2];
#pragma unroll
    for (int mf = 0; mf < 2; mf++)
#pragma unroll
      for (int kc = 0; kc < 2; kc++)
        af[mf][kc] = *(const bf16x8*)(Xl[cur] + (mf * 16 + c) * 128 + ((kc * 64 + 16 * g) ^ swc));
#pragma unroll
    for (int kc = 0; kc < 2; kc++)
#pragma unroll
      for (int n0 = 0; n0 < 6; n0++) {
        bf16x8 wf = *(const bf16x8*)(wb + (size_t)n0 * 16384 + ki * 64 + kc * 32 + 8 * g);
#pragma unroll
        for (int mf = 0; mf < 2; mf++) acc[mf][n0] = mfma16(af[mf][kc], wf, acc[mf][n0]);
      }
    if (ki < 15) XW(cur ^ 1, g0, g1);
    __syncthreads();
  }

  // ---- epilogue (acc[mf][n0][r] = out[m = m0+mf*16+4g+r][wave N-row n0*16+c]) ----
  if (w == 0) {
#pragma unroll
    for (int mf = 0; mf < 2; mf++)
#pragma unroll
      for (int r = 0; r < 4; r++) {
        int mm = m0 + mf * 16 + 4 * g + r;
        int t = mm & 4095;
#pragma unroll
        for (int j = 0; j < 3; j++) {
          int d = j * 16 + c;
          float co = cosT[t * 64 + d], si = sinT[t * 64 + d];
          float lo = acc[mf][j][r], hi = acc[mf][j + 3][r];
          Qb[(size_t)mm * 128 + d] = f2bf(lo * co - hi * si);
          Qb[(size_t)mm * 128 + d + 64] = f2bf(hi * co + lo * si);
        }
      }
  } else if (w == 1) {
#pragma unroll
    for (int mf = 0; mf < 2; mf++) {
#pragma unroll
      for (int r = 0; r < 4; r++) {
        int mm = m0 + mf * 16 + 4 * g + r;
        int t = mm & 4095;
        int d = 48 + c;
        float co = cosT[t * 64 + d], si = sinT[t * 64 + d];
        float lo = acc[mf][0][r], hi = acc[mf][1][r];
        Qb[(size_t)mm * 128 + d] = f2bf(lo * co - hi * si);
        Qb[(size_t)mm * 128 + d + 64] = f2bf(hi * co + lo * si);
      }
      int kp = ((m0 + mf * 16) >> 2) + g;
      int kpos = kp & 1023;
      int ksw = (kp & 7) << 4;
      char* kb2 = Kswz + (size_t)kp * 256;
#pragma unroll
      for (int j = 0; j < 2; j++) {
        int d = j * 16 + c;
        float lo = 0.25f * (acc[mf][2 + j][0] + acc[mf][2 + j][1] + acc[mf][2 + j][2] + acc[mf][2 + j][3]);
        float hi = 0.25f * (acc[mf][4 + j][0] + acc[mf][4 + j][1] + acc[mf][4 + j][2] + acc[mf][4 + j][3]);
        float co = cosT[kpos * 64 + d], si = sinT[kpos * 64 + d];
        *(short*)(kb2 + ((d * 2) ^ ksw)) = f2bf(lo * co - hi * si);
        *(short*)(kb2 + (((d + 64) * 2) ^ ksw)) = f2bf(hi * co + lo * si);
      }
    }
  } else if (w == 2) {
#pragma unroll
    for (int mf = 0; mf < 2; mf++) {
      int kp = ((m0 + mf * 16) >> 2) + g;
      int kpos = kp & 1023, bb = kp >> 10;
      int ksw = (kp & 7) << 4;
      char* kb2 = Kswz + (size_t)kp * 256;
#pragma unroll
      for (int j = 0; j < 2; j++) {
        int d = 32 + j * 16 + c;
        float lo = 0.25f * (acc[mf][j][0] + acc[mf][j][1] + acc[mf][j][2] + acc[mf][j][3]);
        float hi = 0.25f * (acc[mf][2 + j][0] + acc[mf][2 + j][1] + acc[mf][2 + j][2] + acc[mf][2 + j][3]);
        float co = cosT[kpos * 64 + d], si = sinT[kpos * 64 + d];
        *(short*)(kb2 + ((d * 2) ^ ksw)) = f2bf(lo * co - hi * si);
        *(short*)(kb2 + (((d + 64) * 2) ^ ksw)) = f2bf(hi * co + lo * si);
      }
#pragma unroll
      for (int j = 0; j < 2; j++) {
        int dm = j * 16 + c;
        float vp = 0.25f * (acc[mf][4 + j][0] + acc[mf][4 + j][1] + acc[mf][4 + j][2] + acc[mf][4 + j][3]);
        size_t off = ((size_t)(bb * 16 + (kpos >> 6)) * 128 + dm) * 128 +
                     (((kpos & 63) * 2) ^ ((dm & 7) << 4));
        *(short*)(Vswz + off) = f2bf(vp);
      }
    }
  } else {
#pragma unroll
    for (int mf = 0; mf < 2; mf++) {
      int kp = ((m0 + mf * 16) >> 2) + g;
      int kpos = kp & 1023, bb = kp >> 10;
#pragma unroll
      for (int j = 0; j < 6; j++) {
        int dm = 32 + j * 16 + c;
        float vp = 0.25f * (acc[mf][j][0] + acc[mf][j][1] + acc[mf][j][2] + acc[mf][j][3]);
        size_t off = ((size_t)(bb * 16 + (kpos >> 6)) * 128 + dm) * 128 +
                     (((kpos & 63) * 2) ^ ((dm & 7) << 4));
        *(short*)(Vswz + off) = f2bf(vp);
      }
    }
  }
}

// ---- fused two-branch flash attention, mirror-paired block ----
// grid 512, 256 thr = 4 waves: w0,w1 causal rows [q0b, q0b+32); w2,w3 unmasked
// mirror rows [4064-q0b, 4096-q0b); combine through LDS; swapped QK^T.
__global__ __launch_bounds__(256) void attn_kernel(const short* __restrict__ Qb,
                                                   const char* __restrict__ Kswz,
                                                   const char* __restrict__ Vswz,
                                                   const float* __restrict__ alphap,
                                                   float* __restrict__ out) {
  __shared__ __align__(16) char lds[2 * 16384 + 2 * 16384 + 4 * 2304];  // 74752
  char* Kl = lds;
  char* Vl = lds + 32768;
  const int tid = threadIdx.x;
  const int w = tid >> 6, g = (tid >> 4) & 3, c = tid & 15;
  char* Pl = lds + 65536 + w * 2304;
  const int blk = blockIdx.x;
  const int b = blk >> 7, qc = blk & 127;
  const int q0b = qc * 32;
  const int tile_b = qc >> 3;
  const bool isC = (w < 2);
  const int qbase = isC ? (q0b + w * 16) : (4064 - q0b + (w - 2) * 16);
  const int myq = qbase + c;
  const int swc = (c & 7) << 4;

  bf16x8 qf[4];
  {
    const short* qr = Qb + ((size_t)b * T_ + myq) * 128;
#pragma unroll
    for (int kc = 0; kc < 4; kc++) qf[kc] = *(const bf16x8*)(qr + kc * 32 + 8 * g);
  }
  f32x4 acc[8];
#pragma unroll
  for (int n = 0; n < 8; n++) acc[n] = (f32x4){0.f, 0.f, 0.f, 0.f};
  float m = -1e30f, l = 0.f;

  const char* kbB = Kswz + (size_t)b * 262144;
  const char* vbB = Vswz + (size_t)b * 262144;

  auto STG = [&](int tg, char* kd, char* vd) {
    const char* kb = kbB + (size_t)tg * 16384;
    const char* vb = vbB + (size_t)tg * 16384;
#pragma unroll
    for (int j = 0; j < 4; j++) gll16(kb + j * 4096 + tid * 16, kd + j * 4096 + tid * 16);
#pragma unroll
    for (int j = 0; j < 4; j++) gll16(vb + j * 4096 + tid * 16, vd + j * 4096 + tid * 16);
  };

  STG(0, Kl, Vl);

#pragma unroll 1
  for (int tg = 0; tg < 16; tg++) {
    const int cur = (tg & 1) * 16384;
    const int nxt = 16384 - cur;
    if (tg < 15) {
      STG(tg + 1, Kl + nxt, Vl + nxt);
      VMCNT(8);
    } else {
      VMCNT(0);
    }
    __builtin_amdgcn_s_barrier();

    if (!isC || tg <= tile_b) {
      // QK^T swapped: s[n][r] = S[key = tg*64 + 16n + 4g + r][q = myq]
      f32x4 s[4];
#pragma unroll
      for (int n = 0; n < 4; n++) s[n] = (f32x4){0.f, 0.f, 0.f, 0.f};
#pragma unroll
      for (int kc = 0; kc < 4; kc++) {
#pragma unroll
        for (int n = 0; n < 4; n++) {
          int row = 16 * n + c;
          bf16x8 kf = *(const bf16x8*)(Kl + cur + row * 256 + ((kc * 64 + 16 * g) ^ swc));
          s[n] = mfma16(kf, qf[kc], s[n]);
        }
      }
      if (isC && tg == tile_b) {  // boundary mask
        int klim = (myq >> 2) - tg * 64;
#pragma unroll
        for (int n = 0; n < 4; n++)
#pragma unroll
          for (int r = 0; r < 4; r++)
            if (16 * n + 4 * g + r > klim) s[n][r] = -3.0e38f;
      }
      float tm = fmaxf(fmaxf(fmaxf(s[0][0], s[0][1]), fmaxf(s[0][2], s[0][3])),
                       fmaxf(fmaxf(s[1][0], s[1][1]), fmaxf(s[1][2], s[1][3])));
      tm = fmaxf(tm, fmaxf(fmaxf(fmaxf(s[2][0], s[2][1]), fmaxf(s[2][2], s[2][3])),
                           fmaxf(fmaxf(s[3][0], s[3][1]), fmaxf(s[3][2], s[3][3]))));
      tm = fmaxf(tm, __shfl_xor(tm, 16));
      tm = fmaxf(tm, __shfl_xor(tm, 32));
      if (__any(tm > m + 8.f)) {  // defer-max
        float mn = fmaxf(m, tm);
        float sc = __builtin_amdgcn_exp2f(m - mn);
        m = mn;
        l *= sc;
        float s0 = __shfl(sc, 4 * g), s1 = __shfl(sc, 4 * g + 1);
        float s2 = __shfl(sc, 4 * g + 2), s3 = __shfl(sc, 4 * g + 3);
        f32x4 scv = {s0, s1, s2, s3};
#pragma unroll
        for (int n0 = 0; n0 < 8; n0++) acc[n0] *= scv;
      }
      float rsum = 0.f;
#pragma unroll
      for (int n = 0; n < 4; n++) {
        float p0 = __builtin_amdgcn_exp2f(s[n][0] - m);
        float p1 = __builtin_amdgcn_exp2f(s[n][1] - m);
        float p2 = __builtin_amdgcn_exp2f(s[n][2] - m);
        float p3 = __builtin_amdgcn_exp2f(s[n][3] - m);
        rsum += (p0 + p1) + (p2 + p3);
        s16x4 pk = {f2bf(p0), f2bf(p1), f2bf(p2), f2bf(p3)};
        *(s16x4*)(Pl + c * 144 + 32 * n + 8 * g) = pk;
      }
      rsum += __shfl_xor(rsum, 16);
      rsum += __shfl_xor(rsum, 32);
      l += rsum;
      bf16x8 pf0 = *(const bf16x8*)(Pl + c * 144 + 16 * g);
      bf16x8 pf1 = *(const bf16x8*)(Pl + c * 144 + 64 + 16 * g);
#pragma unroll
      for (int n0 = 0; n0 < 8; n0++) {
        const char* vrow = Vl + cur + (n0 * 16 + c) * 128;
        bf16x8 v0 = *(const bf16x8*)(vrow + ((16 * g) ^ swc));
        bf16x8 v1 = *(const bf16x8*)(vrow + ((64 + 16 * g) ^ swc));
        acc[n0] = mfma16(pf0, v0, acc[n0]);
        acc[n0] = mfma16(pf1, v1, acc[n0]);
      }
    }
    __builtin_amdgcn_s_barrier();
  }

  // epilogue: per-output-row 1/l, exchange U through LDS, combine, write
  float lr0 = __shfl(l, 4 * g), lr1 = __shfl(l, 4 * g + 1);
  float lr2 = __shfl(l, 4 * g + 2), lr3 = __shfl(l, 4 * g + 3);
  f32x4 linv = {1.f / lr0, 1.f / lr1, 1.f / lr2, 1.f / lr3};
  float* Ul = (float*)lds;  // [32][132] overlay (all K/V reads done)
  if (!isC) {
#pragma unroll
    for (int n0 = 0; n0 < 8; n0++)
#pragma unroll
      for (int r = 0; r < 4; r++) {
        int urow = 31 - (16 * (w - 2) + 4 * g + r);
        Ul[urow * 132 + n0 * 16 + c] = acc[n0][r] * linv[r];
      }
  }
  __syncthreads();
  if (isC) {
    float alpha = 1.f / (1.f + expf(-alphap[0]));
    float oma = 1.f - alpha;
#pragma unroll
    for (int n0 = 0; n0 < 8; n0++)
#pragma unroll
      for (int r = 0; r < 4; r++) {
        int j = 16 * w + 4 * g + r;
        float uvv = Ul[j * 132 + n0 * 16 + c];
        out[((size_t)b * T_ + q0b + j) * 128 + n0 * 16 + c] =
            alpha * acc[n0][r] * linv[r] + oma * uvv;
      }
  }
}

extern "C" void kernel_launch(void* const* d_in, const int* in_sizes, int n_in,
                              void* d_out, int out_size, void* d_ws, size_t ws_size,
                              hipStream_t stream) {
  const float* x = (const float*)d_in[0];
  const float* Wq = (const float*)d_in[1];
  const float* Wk = (const float*)d_in[2];
  const float* Wv = (const float*)d_in[3];
  const float* falpha = (const float*)d_in[9];
  char* ws = (char*)d_ws;
  float* cosT = (float*)(ws);                  // 1 MB
  float* sinT = (float*)(ws + 1048576);        // 1 MB
  short* WT = (short*)(ws + 2097152);          // 768 KB  [384][1024] bf16, reordered rows
  short* Qb = (short*)(ws + 2883584);          // 4 MB    roped+scaled Q bf16
  char* Kswz = ws + 7077888;                   // 1 MB    roped pooled K bf16, swizzled
  char* Vswz = ws + 8126464;                   // 1 MB    pooled V^T bf16, swizzled tiles

  rope_kernel<<<1024, 256, 0, stream>>>(cosT, sinT);
  wtprep_kernel<<<1536, 256, 0, stream>>>(Wq, Wk, Wv, WT);
  gemm_fused<<<512, 256, 0, stream>>>(x, WT, cosT, sinT, Qb, Kswz, Vswz);
  attn_kernel<<<512, 256, 0, stream>>>(Qb, Kswz, Vswz, falpha, (float*)d_out);
}

// Round 5
// 87.213 us; speedup vs baseline: 1.1520x; 1.1520x over previous
//
#include <hip/hip_runtime.h>
#include <hip/hip_bf16.h>
#include <math.h>

// FluxHead: B=4, T=4096, D_MODEL=1024, HEAD_DIM=128, STRIDE=4, Tk=1024, CAUSAL
// Exact-math simplifications:
//  - spectral gate adds a per-(b,q) scalar to logits -> softmax-invariant -> skipped
//  - reverse branch == unmasked forward attention, output read at mirror row
//  - pooling commutes with K/V projection -> pooled in GEMM epilogue (lane-local)
//  - log2e/SCALE folded into Wq -> softmax in exp2 units

#define T_ 4096
#define TK_ 1024

typedef __attribute__((ext_vector_type(8))) short bf16x8;
typedef __attribute__((ext_vector_type(4))) float f32x4;
typedef __attribute__((ext_vector_type(4))) short s16x4;
typedef __attribute__((address_space(1))) unsigned int gas_u32;
typedef __attribute__((address_space(3))) unsigned int las_u32;

__device__ inline short f2bf(float f) {
  unsigned u = __builtin_bit_cast(unsigned, f);
  u = (u + 0x7FFFu + ((u >> 16) & 1u)) >> 16;
  return (short)u;
}
__device__ inline f32x4 mfma16(bf16x8 a, bf16x8 b, f32x4 c) {
  return __builtin_amdgcn_mfma_f32_16x16x32_bf16(a, b, c, 0, 0, 0);
}
__device__ inline void gll16(const void* g, void* l) {
  __builtin_amdgcn_global_load_lds((gas_u32*)g, (las_u32*)l, 16, 0, 0);
}
#define VMCNT(n) asm volatile("s_waitcnt vmcnt(" #n ")" ::: "memory")

// ---- rope table: cos/sin[t][d], t<4096, d<64 ----
__global__ __launch_bounds__(256) void rope_kernel(float* __restrict__ cosT,
                                                   float* __restrict__ sinT) {
  int i = blockIdx.x * 256 + threadIdx.x;  // 262144
  int t = i >> 6, d = i & 63;
  float theta = powf(10000.f, -(float)d * (1.f / 64.f));
  float fr = (float)t * theta;
  cosT[i] = cosf(fr);
  sinT[i] = sinf(fr);
}

// ---- x f32 -> bf16 pre-cast ----
__global__ __launch_bounds__(256) void xbf_kernel(const float* __restrict__ x,
                                                  short* __restrict__ xb) {
  int i = blockIdx.x * 256 + threadIdx.x;  // 2097152, 8 elems each
  float4 f0 = ((const float4*)x)[(size_t)i * 2];
  float4 f1 = ((const float4*)x)[(size_t)i * 2 + 1];
  bf16x8 o = {f2bf(f0.x), f2bf(f0.y), f2bf(f0.z), f2bf(f0.w),
              f2bf(f1.x), f2bf(f1.y), f2bf(f1.z), f2bf(f1.w)};
  ((bf16x8*)xb)[i] = o;
}

// ---- WT prep: [384][1024] bf16. Sections: [0..127]=Wq*scale, [128..255]=Wk,
// [256..383]=Wv. Within Q and K sections, rows reordered so each wave's 64-col
// slice holds matched rope lo/hi pairs:
//   row n (0..127): wc=n>>6, j=(n>>5)&1, i=n&31 -> actual col = wc*32 + i + j*64
__global__ __launch_bounds__(256) void wtprep_kernel(const float* __restrict__ Wq,
                                                     const float* __restrict__ Wk,
                                                     const float* __restrict__ Wv,
                                                     short* __restrict__ WT) {
  int i = blockIdx.x * 256 + threadIdx.x;  // 384*1024
  int n = i >> 10, k = i & 1023;
  float v;
  if (n < 128) {
    int col = (n >> 6) * 32 + (n & 31) + ((n >> 5) & 1) * 64;
    v = Wq[(size_t)k * 128 + col] * 0.12751741656f;  // log2(e)/sqrt(128)
  } else if (n < 256) {
    int nk = n - 128;
    int col = (nk >> 6) * 32 + (nk & 31) + ((nk >> 5) & 1) * 64;
    v = Wk[(size_t)k * 128 + col];
  } else {
    v = Wv[(size_t)k * 128 + (n - 256)];
  }
  WT[i] = f2bf(v);
}

// ---- projection GEMM, m97-style: grid 768 = 256 M-tiles (BM=64) x 3 N-blocks.
// Block 256 thr = 4 waves (2x2), wave tile 32x64. A,B staged via global_load_lds
// into linear LDS (48 KB dbuf). nb=0 -> Q (rope), nb=1 -> K (pool+rope+swz),
// nb=2 -> V (pool + transposed swz tiles).
__global__ __launch_bounds__(256) void gemm_fused(const short* __restrict__ xb,
                                                  const short* __restrict__ WT,
                                                  const float* __restrict__ cosT,
                                                  const float* __restrict__ sinT,
                                                  short* __restrict__ Qb,
                                                  char* __restrict__ Kswz,
                                                  char* __restrict__ Vswz) {
  __shared__ __align__(16) char Al[2][8192];    // 64 rows x 64 k bf16, pitch 128B
  __shared__ __align__(16) char Bl[2][16384];   // 128 rows x 64 k bf16, pitch 128B
  const int tid = threadIdx.x;
  const int w = tid >> 6, g = (tid >> 4) & 3, c = tid & 15;
  const int wr = w >> 1, wc = w & 1;
  const int mt = blockIdx.x & 255, nb = blockIdx.x >> 8;
  const int m0 = mt * 64;
  const char* xbB = (const char*)xb + (size_t)m0 * 2048;
  const char* WTB = (const char*)WT + (size_t)nb * 128 * 2048;

  f32x4 acc[2][4];
#pragma unroll
  for (int mf = 0; mf < 2; mf++)
#pragma unroll
    for (int n = 0; n < 4; n++) acc[mf][n] = (f32x4){0.f, 0.f, 0.f, 0.f};

  auto STAGE = [&](int ki, char* Ab, char* Bb) {
#pragma unroll
    for (int i2 = 0; i2 < 2; i2++) {
      int j = tid + 256 * i2;
      gll16(xbB + (size_t)(j >> 3) * 2048 + ki * 128 + (j & 7) * 16, Ab + j * 16);
    }
#pragma unroll
    for (int i2 = 0; i2 < 4; i2++) {
      int j = tid + 256 * i2;
      gll16(WTB + (size_t)(j >> 3) * 2048 + ki * 128 + (j & 7) * 16, Bb + j * 16);
    }
  };
  auto COMPUTE = [&](const char* Ab, const char* Bb) {
#pragma unroll
    for (int kc = 0; kc < 2; kc++) {
      bf16x8 af[2], bfr[4];
#pragma unroll
      for (int mf = 0; mf < 2; mf++)
        af[mf] = *(const bf16x8*)(Ab + (wr * 32 + mf * 16 + c) * 128 + kc * 64 + 16 * g);
#pragma unroll
      for (int n0 = 0; n0 < 4; n0++)
        bfr[n0] = *(const bf16x8*)(Bb + (wc * 64 + n0 * 16 + c) * 128 + kc * 64 + 16 * g);
#pragma unroll
      for (int mf = 0; mf < 2; mf++)
#pragma unroll
        for (int n0 = 0; n0 < 4; n0++) acc[mf][n0] = mfma16(af[mf], bfr[n0], acc[mf][n0]);
    }
  };

  STAGE(0, Al[0], Bl[0]);
#pragma unroll 1
  for (int ki = 0; ki < 16; ki += 2) {
    STAGE(ki + 1, Al[1], Bl[1]);
    VMCNT(6);
    __builtin_amdgcn_s_barrier();
    COMPUTE(Al[0], Bl[0]);
    __builtin_amdgcn_s_barrier();
    if (ki + 2 < 16) {
      STAGE(ki + 2, Al[0], Bl[0]);
      VMCNT(6);
    } else {
      VMCNT(0);
    }
    __builtin_amdgcn_s_barrier();
    COMPUTE(Al[1], Bl[1]);
    __builtin_amdgcn_s_barrier();
  }

  // ---- epilogue: acc[mf][n0][r] = C[m0 + wr*32 + mf*16 + 4g + r][wc*64 + n0*16 + c]
  if (nb == 0) {
    // Q: cols reordered -> for n0 in {0,1}: d = wc*32 + n0*16 + c, hi = acc[mf][n0+2]
#pragma unroll
    for (int mf = 0; mf < 2; mf++)
#pragma unroll
      for (int r = 0; r < 4; r++) {
        int mm = m0 + wr * 32 + mf * 16 + 4 * g + r;
        int t = mm & 4095;
#pragma unroll
        for (int n0 = 0; n0 < 2; n0++) {
          int d = wc * 32 + n0 * 16 + c;
          float co = cosT[t * 64 + d], si = sinT[t * 64 + d];
          float lo = acc[mf][n0][r], hi = acc[mf][n0 + 2][r];
          Qb[(size_t)mm * 128 + d] = f2bf(lo * co - hi * si);
          Qb[(size_t)mm * 128 + d + 64] = f2bf(hi * co + lo * si);
        }
      }
  } else if (nb == 1) {
    // K: pool over r (lane-local), rope, swizzled store
#pragma unroll
    for (int mf = 0; mf < 2; mf++) {
      int kp = ((m0 + wr * 32 + mf * 16) >> 2) + g;
      int kpos = kp & 1023;
      int ksw = (kp & 7) << 4;
      char* kb2 = Kswz + (size_t)kp * 256;
#pragma unroll
      for (int n0 = 0; n0 < 2; n0++) {
        int d = wc * 32 + n0 * 16 + c;
        float lo = 0.25f * (acc[mf][n0][0] + acc[mf][n0][1] + acc[mf][n0][2] + acc[mf][n0][3]);
        float hi = 0.25f * (acc[mf][n0 + 2][0] + acc[mf][n0 + 2][1] + acc[mf][n0 + 2][2] + acc[mf][n0 + 2][3]);
        float co = cosT[kpos * 64 + d], si = sinT[kpos * 64 + d];
        *(short*)(kb2 + ((d * 2) ^ ksw)) = f2bf(lo * co - hi * si);
        *(short*)(kb2 + (((d + 64) * 2) ^ ksw)) = f2bf(hi * co + lo * si);
      }
    }
  } else {
    // V: pool over r, transposed swizzled tile store
#pragma unroll
    for (int mf = 0; mf < 2; mf++) {
      int kp = ((m0 + wr * 32 + mf * 16) >> 2) + g;
      int kpos = kp & 1023, bb = kp >> 10;
#pragma unroll
      for (int n0 = 0; n0 < 4; n0++) {
        int d = wc * 64 + n0 * 16 + c;
        float vp = 0.25f * (acc[mf][n0][0] + acc[mf][n0][1] + acc[mf][n0][2] + acc[mf][n0][3]);
        size_t off = ((size_t)(bb * 16 + (kpos >> 6)) * 128 + d) * 128 +
                     (((kpos & 63) * 2) ^ ((d & 7) << 4));
        *(short*)(Vswz + off) = f2bf(vp);
      }
    }
  }
}

// ---- fused two-branch flash attention, mirror-paired block ----
// grid 512, 256 thr = 4 waves: w0,w1 causal rows [q0b, q0b+32); w2,w3 unmasked
// mirror rows [4064-q0b, 4096-q0b); combine through LDS; swapped QK^T.
__global__ __launch_bounds__(256) void attn_kernel(const short* __restrict__ Qb,
                                                   const char* __restrict__ Kswz,
                                                   const char* __restrict__ Vswz,
                                                   const float* __restrict__ alphap,
                                                   float* __restrict__ out) {
  __shared__ __align__(16) char lds[2 * 16384 + 2 * 16384 + 4 * 2304];  // 74752
  char* Kl = lds;
  char* Vl = lds + 32768;
  const int tid = threadIdx.x;
  const int w = tid >> 6, g = (tid >> 4) & 3, c = tid & 15;
  char* Pl = lds + 65536 + w * 2304;
  const int blk = blockIdx.x;
  const int b = blk >> 7, qc = blk & 127;
  const int q0b = qc * 32;
  const int tile_b = qc >> 3;
  const bool isC = (w < 2);
  const int qbase = isC ? (q0b + w * 16) : (4064 - q0b + (w - 2) * 16);
  const int myq = qbase + c;
  const int swc = (c & 7) << 4;

  bf16x8 qf[4];
  {
    const short* qr = Qb + ((size_t)b * T_ + myq) * 128;
#pragma unroll
    for (int kc = 0; kc < 4; kc++) qf[kc] = *(const bf16x8*)(qr + kc * 32 + 8 * g);
  }
  f32x4 acc[8];
#pragma unroll
  for (int n = 0; n < 8; n++) acc[n] = (f32x4){0.f, 0.f, 0.f, 0.f};
  float m = -1e30f, l = 0.f;

  const char* kbB = Kswz + (size_t)b * 262144;
  const char* vbB = Vswz + (size_t)b * 262144;

  auto STG = [&](int tg, char* kd, char* vd) {
    const char* kb = kbB + (size_t)tg * 16384;
    const char* vb = vbB + (size_t)tg * 16384;
#pragma unroll
    for (int j = 0; j < 4; j++) gll16(kb + j * 4096 + tid * 16, kd + j * 4096 + tid * 16);
#pragma unroll
    for (int j = 0; j < 4; j++) gll16(vb + j * 4096 + tid * 16, vd + j * 4096 + tid * 16);
  };

  STG(0, Kl, Vl);

#pragma unroll 1
  for (int tg = 0; tg < 16; tg++) {
    const int cur = (tg & 1) * 16384;
    const int nxt = 16384 - cur;
    if (tg < 15) {
      STG(tg + 1, Kl + nxt, Vl + nxt);
      VMCNT(8);
    } else {
      VMCNT(0);
    }
    __builtin_amdgcn_s_barrier();

    if (!isC || tg <= tile_b) {
      // QK^T swapped: s[n][r] = S[key = tg*64 + 16n + 4g + r][q = myq]
      f32x4 s[4];
#pragma unroll
      for (int n = 0; n < 4; n++) s[n] = (f32x4){0.f, 0.f, 0.f, 0.f};
#pragma unroll
      for (int kc = 0; kc < 4; kc++) {
#pragma unroll
        for (int n = 0; n < 4; n++) {
          int row = 16 * n + c;
          bf16x8 kf = *(const bf16x8*)(Kl + cur + row * 256 + ((kc * 64 + 16 * g) ^ swc));
          s[n] = mfma16(kf, qf[kc], s[n]);
        }
      }
      if (isC && tg == tile_b) {  // boundary mask
        int klim = (myq >> 2) - tg * 64;
#pragma unroll
        for (int n = 0; n < 4; n++)
#pragma unroll
          for (int r = 0; r < 4; r++)
            if (16 * n + 4 * g + r > klim) s[n][r] = -3.0e38f;
      }
      float tm = fmaxf(fmaxf(fmaxf(s[0][0], s[0][1]), fmaxf(s[0][2], s[0][3])),
                       fmaxf(fmaxf(s[1][0], s[1][1]), fmaxf(s[1][2], s[1][3])));
      tm = fmaxf(tm, fmaxf(fmaxf(fmaxf(s[2][0], s[2][1]), fmaxf(s[2][2], s[2][3])),
                           fmaxf(fmaxf(s[3][0], s[3][1]), fmaxf(s[3][2], s[3][3]))));
      tm = fmaxf(tm, __shfl_xor(tm, 16));
      tm = fmaxf(tm, __shfl_xor(tm, 32));
      if (__any(tm > m + 8.f)) {  // defer-max
        float mn = fmaxf(m, tm);
        float sc = __builtin_amdgcn_exp2f(m - mn);
        m = mn;
        l *= sc;
        float s0 = __shfl(sc, 4 * g), s1 = __shfl(sc, 4 * g + 1);
        float s2 = __shfl(sc, 4 * g + 2), s3 = __shfl(sc, 4 * g + 3);
        f32x4 scv = {s0, s1, s2, s3};
#pragma unroll
        for (int n0 = 0; n0 < 8; n0++) acc[n0] *= scv;
      }
      float rsum = 0.f;
#pragma unroll
      for (int n = 0; n < 4; n++) {
        float p0 = __builtin_amdgcn_exp2f(s[n][0] - m);
        float p1 = __builtin_amdgcn_exp2f(s[n][1] - m);
        float p2 = __builtin_amdgcn_exp2f(s[n][2] - m);
        float p3 = __builtin_amdgcn_exp2f(s[n][3] - m);
        rsum += (p0 + p1) + (p2 + p3);
        s16x4 pk = {f2bf(p0), f2bf(p1), f2bf(p2), f2bf(p3)};
        *(s16x4*)(Pl + c * 144 + 32 * n + 8 * g) = pk;
      }
      rsum += __shfl_xor(rsum, 16);
      rsum += __shfl_xor(rsum, 32);
      l += rsum;
      bf16x8 pf0 = *(const bf16x8*)(Pl + c * 144 + 16 * g);
      bf16x8 pf1 = *(const bf16x8*)(Pl + c * 144 + 64 + 16 * g);
#pragma unroll
      for (int n0 = 0; n0 < 8; n0++) {
        const char* vrow = Vl + cur + (n0 * 16 + c) * 128;
        bf16x8 v0 = *(const bf16x8*)(vrow + ((16 * g) ^ swc));
        bf16x8 v1 = *(const bf16x8*)(vrow + ((64 + 16 * g) ^ swc));
        acc[n0] = mfma16(pf0, v0, acc[n0]);
        acc[n0] = mfma16(pf1, v1, acc[n0]);
      }
    }
    __builtin_amdgcn_s_barrier();
  }

  // epilogue: per-output-row 1/l, exchange U through LDS, combine, write
  float lr0 = __shfl(l, 4 * g), lr1 = __shfl(l, 4 * g + 1);
  float lr2 = __shfl(l, 4 * g + 2), lr3 = __shfl(l, 4 * g + 3);
  f32x4 linv = {1.f / lr0, 1.f / lr1, 1.f / lr2, 1.f / lr3};
  float* Ul = (float*)lds;  // [32][132] overlay (all K/V reads done)
  if (!isC) {
#pragma unroll
    for (int n0 = 0; n0 < 8; n0++)
#pragma unroll
      for (int r = 0; r < 4; r++) {
        int urow = 31 - (16 * (w - 2) + 4 * g + r);
        Ul[urow * 132 + n0 * 16 + c] = acc[n0][r] * linv[r];
      }
  }
  __syncthreads();
  if (isC) {
    float alpha = 1.f / (1.f + expf(-alphap[0]));
    float oma = 1.f - alpha;
#pragma unroll
    for (int n0 = 0; n0 < 8; n0++)
#pragma unroll
      for (int r = 0; r < 4; r++) {
        int j = 16 * w + 4 * g + r;
        float uvv = Ul[j * 132 + n0 * 16 + c];
        out[((size_t)b * T_ + q0b + j) * 128 + n0 * 16 + c] =
            alpha * acc[n0][r] * linv[r] + oma * uvv;
      }
  }
}

extern "C" void kernel_launch(void* const* d_in, const int* in_sizes, int n_in,
                              void* d_out, int out_size, void* d_ws, size_t ws_size,
                              hipStream_t stream) {
  const float* x = (const float*)d_in[0];
  const float* Wq = (const float*)d_in[1];
  const float* Wk = (const float*)d_in[2];
  const float* Wv = (const float*)d_in[3];
  const float* falpha = (const float*)d_in[9];
  char* ws = (char*)d_ws;
  float* cosT = (float*)(ws);                  // 1 MB
  float* sinT = (float*)(ws + 1048576);        // 1 MB
  short* WT = (short*)(ws + 2097152);          // 768 KB  [384][1024] bf16, reordered rows
  short* Qb = (short*)(ws + 2883584);          // 4 MB    roped+scaled Q bf16
  char* Kswz = ws + 7077888;                   // 1 MB    roped pooled K bf16, swizzled
  char* Vswz = ws + 8126464;                   // 1 MB    pooled V^T bf16, swizzled tiles
  short* xb = (short*)(ws + 9175040);          // 32 MB   x as bf16

  rope_kernel<<<1024, 256, 0, stream>>>(cosT, sinT);
  wtprep_kernel<<<1536, 256, 0, stream>>>(Wq, Wk, Wv, WT);
  xbf_kernel<<<8192, 256, 0, stream>>>(x, xb);
  gemm_fused<<<768, 256, 0, stream>>>(xb, WT, cosT, sinT, Qb, Kswz, Vswz);
  attn_kernel<<<512, 256, 0, stream>>>(Qb, Kswz, Vswz, falpha, (float*)d_out);
}

// Round 8
// 77.039 us; speedup vs baseline: 1.3041x; 1.1321x over previous
//
#include <hip/hip_runtime.h>
#include <hip/hip_bf16.h>
#include <math.h>

// FluxHead: B=4, T=4096, D_MODEL=1024, HEAD_DIM=128, STRIDE=4, Tk=1024, CAUSAL
// Exact-math simplifications:
//  - spectral gate adds a per-(b,q) scalar to logits -> softmax-invariant -> skipped
//  - reverse branch == unmasked forward attention, output read at mirror row
//  - pooling commutes with K/V projection -> pooled in GEMM epilogue (lane-local)
//  - log2e/SCALE folded into Wq -> softmax in exp2 units

#define T_ 4096
#define TK_ 1024

typedef __attribute__((ext_vector_type(8))) short bf16x8;
typedef __attribute__((ext_vector_type(4))) float f32x4;
typedef __attribute__((ext_vector_type(4))) short s16x4;
typedef __attribute__((address_space(1))) unsigned int gas_u32;
typedef __attribute__((address_space(3))) unsigned int las_u32;

__device__ inline short f2bf(float f) {
  unsigned u = __builtin_bit_cast(unsigned, f);
  u = (u + 0x7FFFu + ((u >> 16) & 1u)) >> 16;
  return (short)u;
}
__device__ inline f32x4 mfma16(bf16x8 a, bf16x8 b, f32x4 c) {
  return __builtin_amdgcn_mfma_f32_16x16x32_bf16(a, b, c, 0, 0, 0);
}
__device__ inline void gll16(const void* g, void* l) {
  __builtin_amdgcn_global_load_lds((gas_u32*)g, (las_u32*)l, 16, 0, 0);
}
#define VMCNT(n) asm volatile("s_waitcnt vmcnt(" #n ")" ::: "memory")

// ---- rope table: cos/sin[t][d], t<4096, d<64 ----
__global__ __launch_bounds__(256) void rope_kernel(float* __restrict__ cosT,
                                                   float* __restrict__ sinT) {
  int i = blockIdx.x * 256 + threadIdx.x;  // 262144
  int t = i >> 6, d = i & 63;
  float theta = powf(10000.f, -(float)d * (1.f / 64.f));
  float fr = (float)t * theta;
  cosT[i] = cosf(fr);
  sinT[i] = sinf(fr);
}

// ---- WT prep: [384][1024] bf16, PRE-SWIZZLED bytes within each 128B k-block:
// byte = ((k&63)*2) ^ ((n&7)<<4). Sections: [0..127]=Wq*scale, [128..255]=Wk,
// [256..383]=Wv. Q/K rows reordered so each wave's 64-col slice holds matched
// rope lo/hi pairs: row n: col = (n>>6)*32 + (n&31) + ((n>>5)&1)*64.
__global__ __launch_bounds__(256) void wtprep_kernel(const float* __restrict__ Wq,
                                                     const float* __restrict__ Wk,
                                                     const float* __restrict__ Wv,
                                                     char* __restrict__ WT) {
  int i = blockIdx.x * 256 + threadIdx.x;  // 384*1024
  int n = i >> 10, k = i & 1023;
  float v;
  if (n < 128) {
    int col = (n >> 6) * 32 + (n & 31) + ((n >> 5) & 1) * 64;
    v = Wq[(size_t)k * 128 + col] * 0.12751741656f;  // log2(e)/sqrt(128)
  } else if (n < 256) {
    int nk = n - 128;
    int col = (nk >> 6) * 32 + (nk & 31) + ((nk >> 5) & 1) * 64;
    v = Wk[(size_t)k * 128 + col];
  } else {
    v = Wv[(size_t)k * 128 + (n - 256)];
  }
  size_t off = (size_t)n * 2048 + (size_t)(k >> 6) * 128 + (((k & 63) * 2) ^ ((n & 7) << 4));
  *(short*)(WT + off) = f2bf(v);
}

// ---- projection GEMM: grid 768 = 8 XCD x (32 M-tiles x 3 N-blocks).
// Trio (same M-tile, 3 N-blocks) co-located on one XCD for x L2 reuse.
// BISECT ROUND: conservative sync — single-buffered LDS + __syncthreads()
// (full vmcnt/lgkm drain, guaranteed correct). x(ki+1) reg-prefetch issued
// between barriers so HBM latency hides under COMPUTE.
__global__ __launch_bounds__(256) void gemm_fused(const float* __restrict__ x,
                                                  const char* __restrict__ WT,
                                                  const float* __restrict__ cosT,
                                                  const float* __restrict__ sinT,
                                                  short* __restrict__ Qb,
                                                  char* __restrict__ Kswz,
                                                  char* __restrict__ Vswz) {
  __shared__ __align__(16) char Al[8192];    // 64 rows x 64 k bf16, swizzled
  __shared__ __align__(16) char Bl[16384];   // 128 rows x 64 k bf16, pre-swz copy
  const int tid = threadIdx.x;
  const int w = tid >> 6, g = (tid >> 4) & 3, c = tid & 15;
  const int wr = w >> 1, wc = w & 1;
  const int swc = (c & 7) << 4;
  // grid decode: trio packing per XCD
  const int x8 = blockIdx.x & 7, jj0 = blockIdx.x >> 3;  // jj0: 0..95
  const int nb = jj0 % 3, tl = jj0 / 3;                  // 32 trios per XCD
  const int mt = x8 * 32 + tl;
  const int m0 = mt * 64;
  const char* WTB = WT + (size_t)nb * 128 * 2048;
  // A staging role
  const int arow = tid >> 2, apart = tid & 3;
  const int sws = (arow & 7) << 4;
  const float* xsrc = x + (size_t)(m0 + arow) * 1024 + apart * 16;

  f32x4 acc[2][4];
#pragma unroll
  for (int mf = 0; mf < 2; mf++)
#pragma unroll
    for (int n = 0; n < 4; n++) acc[mf][n] = (f32x4){0.f, 0.f, 0.f, 0.f};

  float4 areg[4];
  auto ALOAD = [&](int ki) {
#pragma unroll
    for (int t = 0; t < 4; t++) areg[t] = *(const float4*)(xsrc + (size_t)ki * 64 + t * 4);
  };
  auto AWRITE = [&]() {
    bf16x8 v0 = {f2bf(areg[0].x), f2bf(areg[0].y), f2bf(areg[0].z), f2bf(areg[0].w),
                 f2bf(areg[1].x), f2bf(areg[1].y), f2bf(areg[1].z), f2bf(areg[1].w)};
    bf16x8 v1 = {f2bf(areg[2].x), f2bf(areg[2].y), f2bf(areg[2].z), f2bf(areg[2].w),
                 f2bf(areg[3].x), f2bf(areg[3].y), f2bf(areg[3].z), f2bf(areg[3].w)};
    *(bf16x8*)(Al + arow * 128 + ((apart * 32) ^ sws)) = v0;
    *(bf16x8*)(Al + arow * 128 + ((apart * 32 + 16) ^ sws)) = v1;
  };
  auto BSTAGE = [&](int ki) {
#pragma unroll
    for (int i2 = 0; i2 < 4; i2++) {
      int j = tid + 256 * i2;
      gll16(WTB + (size_t)(j >> 3) * 2048 + ki * 128 + (j & 7) * 16, Bl + j * 16);
    }
  };
  auto COMPUTE = [&]() {
#pragma unroll
    for (int kc = 0; kc < 2; kc++) {
      bf16x8 af[2], bfr[4];
#pragma unroll
      for (int mf = 0; mf < 2; mf++)
        af[mf] = *(const bf16x8*)(Al + (wr * 32 + mf * 16 + c) * 128 + ((kc * 64 + 16 * g) ^ swc));
#pragma unroll
      for (int n0 = 0; n0 < 4; n0++)
        bfr[n0] = *(const bf16x8*)(Bl + (wc * 64 + n0 * 16 + c) * 128 + ((kc * 64 + 16 * g) ^ swc));
#pragma unroll
      for (int mf = 0; mf < 2; mf++)
#pragma unroll
        for (int n0 = 0; n0 < 4; n0++) acc[mf][n0] = mfma16(af[mf], bfr[n0], acc[mf][n0]);
    }
  };

  ALOAD(0);
#pragma unroll 1
  for (int ki = 0; ki < 16; ki++) {
    AWRITE();                 // x(ki) regs -> LDS (bf16, swizzled)
    BSTAGE(ki);               // W(ki) gll -> LDS
    __syncthreads();          // full drain: gll + lgkm complete, all waves
    if (ki + 1 < 16) ALOAD(ki + 1);  // issue x(ki+1); lands during COMPUTE
    COMPUTE();
    __syncthreads();          // drains the prefetch loads too (covered by MFMA time)
  }

  // ---- epilogue: acc[mf][n0][r] = C[m0 + wr*32 + mf*16 + 4g + r][wc*64 + n0*16 + c]
  if (nb == 0) {
#pragma unroll
    for (int mf = 0; mf < 2; mf++)
#pragma unroll
      for (int r = 0; r < 4; r++) {
        int mm = m0 + wr * 32 + mf * 16 + 4 * g + r;
        int t = mm & 4095;
#pragma unroll
        for (int n0 = 0; n0 < 2; n0++) {
          int d = wc * 32 + n0 * 16 + c;
          float co = cosT[t * 64 + d], si = sinT[t * 64 + d];
          float lo = acc[mf][n0][r], hi = acc[mf][n0 + 2][r];
          Qb[(size_t)mm * 128 + d] = f2bf(lo * co - hi * si);
          Qb[(size_t)mm * 128 + d + 64] = f2bf(hi * co + lo * si);
        }
      }
  } else if (nb == 1) {
#pragma unroll
    for (int mf = 0; mf < 2; mf++) {
      int kp = ((m0 + wr * 32 + mf * 16) >> 2) + g;
      int kpos = kp & 1023;
      int ksw = (kp & 7) << 4;
      char* kb2 = Kswz + (size_t)kp * 256;
#pragma unroll
      for (int n0 = 0; n0 < 2; n0++) {
        int d = wc * 32 + n0 * 16 + c;
        float lo = 0.25f * (acc[mf][n0][0] + acc[mf][n0][1] + acc[mf][n0][2] + acc[mf][n0][3]);
        float hi = 0.25f * (acc[mf][n0 + 2][0] + acc[mf][n0 + 2][1] + acc[mf][n0 + 2][2] + acc[mf][n0 + 2][3]);
        float co = cosT[kpos * 64 + d], si = sinT[kpos * 64 + d];
        *(short*)(kb2 + ((d * 2) ^ ksw)) = f2bf(lo * co - hi * si);
        *(short*)(kb2 + (((d + 64) * 2) ^ ksw)) = f2bf(hi * co + lo * si);
      }
    }
  } else {
    // V: pool over r, store [b][tile32][128 d][32 k], byte swz (k*2)^((d&3)<<4)
#pragma unroll
    for (int mf = 0; mf < 2; mf++) {
      int kp = ((m0 + wr * 32 + mf * 16) >> 2) + g;
      int kpos = kp & 1023, bb = kp >> 10;
#pragma unroll
      for (int n0 = 0; n0 < 4; n0++) {
        int d = wc * 64 + n0 * 16 + c;
        float vp = 0.25f * (acc[mf][n0][0] + acc[mf][n0][1] + acc[mf][n0][2] + acc[mf][n0][3]);
        size_t off = ((size_t)(bb * 32 + (kpos >> 5)) * 128 + d) * 64 +
                     (((kpos & 31) * 2) ^ ((d & 3) << 4));
        *(short*)(Vswz + off) = f2bf(vp);
      }
    }
  }
}

// ---- fused two-branch flash attention, mirror-paired block, KVBLK=32 ----
// grid 512, 256 thr = 4 waves: w0,w1 causal rows [q0b, q0b+32); w2,w3 unmasked
// mirror rows; combine through LDS; swapped QK^T (lane-local softmax).
// LDS 37 KB -> 4 blocks/CU (16 waves).  [UNCHANGED from round 7 for bisection]
__global__ __launch_bounds__(256, 4) void attn_kernel(const short* __restrict__ Qb,
                                                      const char* __restrict__ Kswz,
                                                      const char* __restrict__ Vswz,
                                                      const float* __restrict__ alphap,
                                                      float* __restrict__ out) {
  __shared__ __align__(16) char lds[2 * 8192 + 2 * 8192 + 4 * 1280];  // 37888
  char* Kl = lds;            // 2 bufs x [32 keys x 256B] (pre-swz rows)
  char* Vl = lds + 16384;    // 2 bufs x [128 d x 64B]    (pre-swz rows)
  const int tid = threadIdx.x;
  const int w = tid >> 6, g = (tid >> 4) & 3, c = tid & 15;
  char* Pl = lds + 32768 + w * 1280;
  const int blk = blockIdx.x;
  const int b = blk >> 7, qc = blk & 127;
  const int q0b = qc * 32;
  const bool isC = (w < 2);
  const int qbase = isC ? (q0b + w * 16) : (4064 - q0b + (w - 2) * 16);
  const int myq = qbase + c;
  const int tile_b = qbase >> 7;  // boundary 32-key tile for this wave
  const int swc = (c & 7) << 4;
  const int vsw = (c & 3) << 4;

  bf16x8 qf[4];
  {
    const short* qr = Qb + ((size_t)b * T_ + myq) * 128;
#pragma unroll
    for (int kc = 0; kc < 4; kc++) qf[kc] = *(const bf16x8*)(qr + kc * 32 + 8 * g);
  }
  f32x4 acc[8];
#pragma unroll
  for (int n = 0; n < 8; n++) acc[n] = (f32x4){0.f, 0.f, 0.f, 0.f};
  float m = -1e30f, l = 0.f;

  const char* kbB = Kswz + (size_t)b * 262144;
  const char* vbB = Vswz + (size_t)b * 262144;

  auto STG = [&](int tg, char* kd, char* vd) {
    const char* kb = kbB + (size_t)tg * 8192;
    const char* vb = vbB + (size_t)tg * 8192;
#pragma unroll
    for (int j = 0; j < 2; j++) gll16(kb + j * 4096 + tid * 16, kd + j * 4096 + tid * 16);
#pragma unroll
    for (int j = 0; j < 2; j++) gll16(vb + j * 4096 + tid * 16, vd + j * 4096 + tid * 16);
  };

  STG(0, Kl, Vl);

#pragma unroll 1
  for (int tg = 0; tg < 32; tg++) {
    const int cur = (tg & 1) * 8192;
    const int nxt = 8192 - cur;
    if (tg < 31) {
      STG(tg + 1, Kl + nxt, Vl + nxt);
      VMCNT(4);
    } else {
      VMCNT(0);
    }
    __builtin_amdgcn_s_barrier();

    if (!isC || tg <= tile_b) {
      // QK^T swapped: s[n][r] = S[key = tg*32 + 16n + 4g + r][q = myq]
      f32x4 s[2];
#pragma unroll
      for (int n = 0; n < 2; n++) s[n] = (f32x4){0.f, 0.f, 0.f, 0.f};
#pragma unroll
      for (int kc = 0; kc < 4; kc++) {
#pragma unroll
        for (int n = 0; n < 2; n++) {
          bf16x8 kf = *(const bf16x8*)(Kl + cur + (16 * n + c) * 256 + ((kc * 64 + 16 * g) ^ swc));
          s[n] = mfma16(kf, qf[kc], s[n]);
        }
      }
      if (isC && tg == tile_b) {  // boundary mask
        int klim = (myq >> 2) - tg * 32;
#pragma unroll
        for (int n = 0; n < 2; n++)
#pragma unroll
          for (int r = 0; r < 4; r++)
            if (16 * n + 4 * g + r > klim) s[n][r] = -3.0e38f;
      }
      float tm = fmaxf(fmaxf(fmaxf(s[0][0], s[0][1]), fmaxf(s[0][2], s[0][3])),
                       fmaxf(fmaxf(s[1][0], s[1][1]), fmaxf(s[1][2], s[1][3])));
      tm = fmaxf(tm, __shfl_xor(tm, 16));
      tm = fmaxf(tm, __shfl_xor(tm, 32));
      if (__any(tm > m + 8.f)) {  // defer-max
        float mn = fmaxf(m, tm);
        float sc = __builtin_amdgcn_exp2f(m - mn);
        m = mn;
        l *= sc;
        float s0 = __shfl(sc, 4 * g), s1 = __shfl(sc, 4 * g + 1);
        float s2 = __shfl(sc, 4 * g + 2), s3 = __shfl(sc, 4 * g + 3);
        f32x4 scv = {s0, s1, s2, s3};
#pragma unroll
        for (int n0 = 0; n0 < 8; n0++) acc[n0] *= scv;
      }
      float rsum = 0.f;
#pragma unroll
      for (int n = 0; n < 2; n++) {
        float p0 = __builtin_amdgcn_exp2f(s[n][0] - m);
        float p1 = __builtin_amdgcn_exp2f(s[n][1] - m);
        float p2 = __builtin_amdgcn_exp2f(s[n][2] - m);
        float p3 = __builtin_amdgcn_exp2f(s[n][3] - m);
        rsum += (p0 + p1) + (p2 + p3);
        s16x4 pk = {f2bf(p0), f2bf(p1), f2bf(p2), f2bf(p3)};
        *(s16x4*)(Pl + c * 80 + 32 * n + 8 * g) = pk;
      }
      rsum += __shfl_xor(rsum, 16);
      rsum += __shfl_xor(rsum, 32);
      l += rsum;
      bf16x8 pf0 = *(const bf16x8*)(Pl + c * 80 + 16 * g);
#pragma unroll
      for (int n0 = 0; n0 < 8; n0++) {
        bf16x8 v0 = *(const bf16x8*)(Vl + cur + (n0 * 16 + c) * 64 + ((16 * g) ^ vsw));
        acc[n0] = mfma16(pf0, v0, acc[n0]);
      }
    }
    __builtin_amdgcn_s_barrier();
  }

  // epilogue: per-output-row 1/l, exchange U through LDS, combine, write
  float lr0 = __shfl(l, 4 * g), lr1 = __shfl(l, 4 * g + 1);
  float lr2 = __shfl(l, 4 * g + 2), lr3 = __shfl(l, 4 * g + 3);
  f32x4 linv = {1.f / lr0, 1.f / lr1, 1.f / lr2, 1.f / lr3};
  float* Ul = (float*)lds;  // [32][132] overlay (16.9 KB <= 37.9 KB)
  if (!isC) {
#pragma unroll
    for (int n0 = 0; n0 < 8; n0++)
#pragma unroll
      for (int r = 0; r < 4; r++) {
        int urow = 31 - (16 * (w - 2) + 4 * g + r);
        Ul[urow * 132 + n0 * 16 + c] = acc[n0][r] * linv[r];
      }
  }
  __syncthreads();
  if (isC) {
    float alpha = 1.f / (1.f + expf(-alphap[0]));
    float oma = 1.f - alpha;
#pragma unroll
    for (int n0 = 0; n0 < 8; n0++)
#pragma unroll
      for (int r = 0; r < 4; r++) {
        int j = 16 * w + 4 * g + r;
        float uvv = Ul[j * 132 + n0 * 16 + c];
        out[((size_t)b * T_ + q0b + j) * 128 + n0 * 16 + c] =
            alpha * acc[n0][r] * linv[r] + oma * uvv;
      }
  }
}

extern "C" void kernel_launch(void* const* d_in, const int* in_sizes, int n_in,
                              void* d_out, int out_size, void* d_ws, size_t ws_size,
                              hipStream_t stream) {
  const float* x = (const float*)d_in[0];
  const float* Wq = (const float*)d_in[1];
  const float* Wk = (const float*)d_in[2];
  const float* Wv = (const float*)d_in[3];
  const float* falpha = (const float*)d_in[9];
  char* ws = (char*)d_ws;
  float* cosT = (float*)(ws);                  // 1 MB
  float* sinT = (float*)(ws + 1048576);        // 1 MB
  char* WT = ws + 2097152;                     // 768 KB  [384][1024] bf16, pre-swizzled
  short* Qb = (short*)(ws + 2883584);          // 4 MB    roped+scaled Q bf16
  char* Kswz = ws + 7077888;                   // 1 MB    roped pooled K bf16, swizzled
  char* Vswz = ws + 8126464;                   // 1 MB    pooled V, 32-key tiles, swizzled

  rope_kernel<<<1024, 256, 0, stream>>>(cosT, sinT);
  wtprep_kernel<<<1536, 256, 0, stream>>>(Wq, Wk, Wv, WT);
  gemm_fused<<<768, 256, 0, stream>>>(x, WT, cosT, sinT, Qb, Kswz, Vswz);
  attn_kernel<<<512, 256, 0, stream>>>(Qb, Kswz, Vswz, falpha, (float*)d_out);
}